// Round 1
// baseline (110.376 us; speedup 1.0000x reference)
//
#include <hip/hip_runtime.h>
#include <hip/hip_bf16.h>

// Problem geometry (fixed by the reference)
constexpr int B = 16, K = 100, H = 120, W = 160;
constexpr int HW  = H * W;          // 19200
constexpr int NF4 = HW / 4;         // 4800 float4 per map
constexpr int BK  = B * K;          // 1600 maps per tensor
constexpr int W4  = W / 4;          // 40 float4 per row

// Flat f32 output layout (concatenated in reference return order)
constexpr size_t OFF_DK   = 0;                       // Dk        [B,K,H,W]
constexpr size_t OFF_KP   = (size_t)BK * HW;         // keypoint  [B,3K,3]
constexpr size_t OFF_ZETA = OFF_KP + (size_t)B*3*K*3;// get_zeta  [B,K]
constexpr size_t OFF_TFDK = OFF_ZETA + BK;           // tf_Dk     [B,K,H,W]
constexpr size_t OFF_TFKP = OFF_TFDK + (size_t)BK*HW;// tf_keypoint [B,3K,3]

// Kernel 1: sigmoid + per-map reductions.
// grid.x = 2*BK blocks; block handles one (tensor, b, k) map.
__global__ __launch_bounds__(256)
void sigmoid_reduce_kernel(const float* __restrict__ Rk,
                           const float* __restrict__ tfRk,
                           float* __restrict__ out,
                           double* __restrict__ ws) {
    const int blk    = blockIdx.x;
    const int tensor = (blk >= BK) ? 1 : 0;
    const int bk     = blk - tensor * BK;
    const float* src = tensor ? tfRk : Rk;
    float*       dst = out + (tensor ? OFF_TFDK : OFF_DK);

    const float4* __restrict__ s4 = (const float4*)(src + (size_t)bk * HW);
    float4*       __restrict__ d4 = (float4*)(dst + (size_t)bk * HW);

    const int tid = threadIdx.x;
    double sum = 0.0, sx = 0.0, sy = 0.0;

    for (int i = tid; i < NF4; i += 256) {
        float4 v = s4[i];
        float4 o;
        o.x = 1.0f / (1.0f + expf(-v.x));
        o.y = 1.0f / (1.0f + expf(-v.y));
        o.z = 1.0f / (1.0f + expf(-v.z));
        o.w = 1.0f / (1.0f + expf(-v.w));
        d4[i] = o;

        const int y  = i / W4;
        const int x0 = (i - y * W4) * 4;
        const double dx0 = (double)o.x, dx1 = (double)o.y,
                     dx2 = (double)o.z, dx3 = (double)o.w;
        const double rs = dx0 + dx1 + dx2 + dx3;
        sum += rs;
        sy  += rs * (double)y;
        sx  += dx0 * (double)(x0)     + dx1 * (double)(x0 + 1)
             + dx2 * (double)(x0 + 2) + dx3 * (double)(x0 + 3);
    }

    // wave (64-lane) reduction
    for (int off = 32; off > 0; off >>= 1) {
        sum += __shfl_down(sum, off);
        sx  += __shfl_down(sx,  off);
        sy  += __shfl_down(sy,  off);
    }
    __shared__ double red[3][4];
    const int wave = tid >> 6, lane = tid & 63;
    if (lane == 0) { red[0][wave] = sum; red[1][wave] = sx; red[2][wave] = sy; }
    __syncthreads();
    if (tid == 0) {
        const double S = red[0][0] + red[0][1] + red[0][2] + red[0][3];
        const double X = red[1][0] + red[1][1] + red[1][2] + red[1][3];
        const double Y = red[2][0] + red[2][1] + red[2][2] + red[2][3];
        ws[(size_t)(tensor * 3 + 0) * BK + bk] = S;
        ws[(size_t)(tensor * 3 + 1) * BK + bk] = X;
        ws[(size_t)(tensor * 3 + 2) * BK + bk] = Y;
        if (tensor == 0) out[OFF_ZETA + bk] = (float)S;
    }
}

// Kernel 2: keypoint extraction, one thread per (tensor, b, k).
__global__ __launch_bounds__(256)
void keypoint_kernel(const double* __restrict__ ws, float* __restrict__ out) {
    const int t = blockIdx.x * 256 + threadIdx.x;
    if (t >= 2 * BK) return;
    const int tensor = t / BK;
    const int bk     = t - tensor * BK;
    const int b = bk / K, k = bk - b * K;

    const double S = ws[(size_t)(tensor * 3 + 0) * BK + bk];
    const double X = ws[(size_t)(tensor * 3 + 1) * BK + bk];
    const double Y = ws[(size_t)(tensor * 3 + 2) * BK + bk];

    const float fz = (float)S;
    const float kx = rintf((float)X / fz);   // RNE matches jnp.round
    const float ky = rintf((float)Y / fz);

    const float* map     = out + (tensor ? OFF_TFDK : OFF_DK) + (size_t)bk * HW; // s, s1
    const float* mainmap = out + OFF_DK + (size_t)bk * HW;                       // s2 (bug-faithful)

    const int gx = (int)kx, gy = (int)ky;
    const float s = map[gy * W + gx];

    // mul then add (NOT fma) to match jnp's kp + kp*s, then int32 truncation
    const int kp1x = (int)__fadd_rn(kx, __fmul_rn(kx, s));
    const int kp1y = (int)__fadd_rn(ky, __fmul_rn(ky, s));
    const int kp2x = (int)__fsub_rn(kx, __fmul_rn(kx, s));
    const int kp2y = (int)__fsub_rn(ky, __fmul_rn(ky, s));

    const int w1 = min(max(kp1x, 0), W - 1), h1 = min(max(kp1y, 0), H - 1);
    const int w2 = min(max(kp2x, 0), W - 1), h2 = min(max(kp2y, 0), H - 1);
    const float s1 = map[h1 * W + w1];
    const float s2 = mainmap[h2 * W + w2];

    float* okp = out + (tensor ? OFF_TFKP : OFF_KP);
    float* r0 = okp + ((size_t)b * 3 * K + k) * 3;
    r0[0] = kx;           r0[1] = ky;           r0[2] = s;
    float* r1 = okp + ((size_t)b * 3 * K + K + k) * 3;
    r1[0] = (float)kp1x;  r1[1] = (float)kp1y;  r1[2] = s1;
    float* r2 = okp + ((size_t)b * 3 * K + 2 * K + k) * 3;
    r2[0] = (float)kp2x;  r2[1] = (float)kp2y;  r2[2] = s2;
}

extern "C" void kernel_launch(void* const* d_in, const int* in_sizes, int n_in,
                              void* d_out, int out_size, void* d_ws, size_t ws_size,
                              hipStream_t stream) {
    const float* Rk   = (const float*)d_in[0];
    const float* tfRk = (const float*)d_in[1];
    float*  out = (float*)d_out;
    double* ws  = (double*)d_ws;   // needs 2*3*1600*8 = 76.8 KB

    sigmoid_reduce_kernel<<<2 * BK, 256, 0, stream>>>(Rk, tfRk, out, ws);
    const int nkp = 2 * BK;
    keypoint_kernel<<<(nkp + 255) / 256, 256, 0, stream>>>(ws, out);
}